// Round 1
// baseline (183.781 us; speedup 1.0000x reference)
//
#include <hip/hip_runtime.h>

// Haar wavedec over 12 levels on last dim (4096) == row-sum * (1/sqrt(2))^12
// = row-sum / 64. Pure memory-bound row reduction.
//
// Layout: x is (128, 512, 4096) fp32 contiguous -> 65536 rows of 4096 floats.
// One wave (64 lanes) per row: 16 float4 loads/lane (coalesced), local
// accumulate, 6-step __shfl_xor wave reduce, single store.

__global__ __launch_bounds__(256) void haar_rowsum_kernel(
    const float* __restrict__ x, float* __restrict__ out, int nrows) {
    const int gtid = blockIdx.x * blockDim.x + threadIdx.x;
    const int row  = gtid >> 6;          // one wave64 per row
    const int lane = threadIdx.x & 63;
    if (row >= nrows) return;

    const float4* rowp = reinterpret_cast<const float4*>(x + (size_t)row * 4096);

    float4 acc = make_float4(0.f, 0.f, 0.f, 0.f);
#pragma unroll
    for (int j = 0; j < 16; ++j) {
        float4 v = rowp[j * 64 + lane];  // lane-contiguous 16B -> 1KiB/wave/instr
        acc.x += v.x;
        acc.y += v.y;
        acc.z += v.z;
        acc.w += v.w;
    }
    float s = (acc.x + acc.y) + (acc.z + acc.w);

    // wave-64 butterfly reduction
#pragma unroll
    for (int off = 32; off >= 1; off >>= 1)
        s += __shfl_xor(s, off, 64);

    if (lane == 0)
        out[row] = s * 0.015625f;  // (1/sqrt(2))^12 == 1/64 exactly
}

extern "C" void kernel_launch(void* const* d_in, const int* in_sizes, int n_in,
                              void* d_out, int out_size, void* d_ws, size_t ws_size,
                              hipStream_t stream) {
    const float* x = (const float*)d_in[0];
    float* out = (float*)d_out;
    const int nrows = out_size;              // 128*512 = 65536 rows
    const int threads = 256;                 // 4 waves -> 4 rows per block
    const int rows_per_block = threads / 64;
    const int blocks = (nrows + rows_per_block - 1) / rows_per_block;
    haar_rowsum_kernel<<<blocks, threads, 0, stream>>>(x, out, nrows);
}